// Round 2
// baseline (1015.805 us; speedup 1.0000x reference)
//
#include <hip/hip_runtime.h>
#include <hip/hip_bf16.h>
#include <math.h>

#define T_ 4096
#define H_ 1024
#define E_ 8
#define KTOP 2
#define I_ 2048
#define EPS_ 1e-5f

using bf16x8 = __attribute__((ext_vector_type(8))) short;
using f32x4  = __attribute__((ext_vector_type(4))) float;

static __device__ __forceinline__ unsigned short f2bf(float f) {
    union { float f; unsigned int u; } v; v.f = f;
    unsigned int u = v.u;
    u += 0x7fffu + ((u >> 16) & 1u);   // RNE
    return (unsigned short)(u >> 16);
}

static __device__ __forceinline__ void gl_lds16(const void* g, void* l) {
    __builtin_amdgcn_global_load_lds(
        (const __attribute__((address_space(1))) unsigned int*)g,
        (__attribute__((address_space(3))) unsigned int*)l, 16, 0, 0);
}

// ---------------- Kernel 0: fp32 -> bf16 weight preconvert -----------------
__global__ __launch_bounds__(256) void k_convert(
    const float* __restrict__ src, unsigned short* __restrict__ dst)
{
    size_t i = (size_t)blockIdx.x * 256 + threadIdx.x;
    const float4* s = (const float4*)src + i * 2;
    float4 a = s[0], b = s[1];
    ushort4 lo, hi;
    lo.x = f2bf(a.x); lo.y = f2bf(a.y); lo.z = f2bf(a.z); lo.w = f2bf(a.w);
    hi.x = f2bf(b.x); hi.y = f2bf(b.y); hi.z = f2bf(b.z); hi.w = f2bf(b.w);
    ((ushort4*)dst)[i * 2]     = lo;
    ((ushort4*)dst)[i * 2 + 1] = hi;
}

// ---------------- Kernel 1: RMSNorm + gate logits + top-2 routing ----------
__global__ __launch_bounds__(256) void k_norm_gate(
    const float* __restrict__ x, const float* __restrict__ scale,
    const float* __restrict__ gk, const float* __restrict__ gb,
    unsigned short* __restrict__ normed_bf,
    int* __restrict__ counts, int* __restrict__ tok_list, float* __restrict__ w_list)
{
    int t = blockIdx.x;
    int tid = threadIdx.x;
    int lane = tid & 63, wave = tid >> 6;

    float4 xv = ((const float4*)(x + (size_t)t * H_))[tid];
    float ss = xv.x*xv.x + xv.y*xv.y + xv.z*xv.z + xv.w*xv.w;
    #pragma unroll
    for (int off = 32; off; off >>= 1) ss += __shfl_down(ss, off);

    __shared__ float red[4];
    __shared__ float s_inv;
    if (lane == 0) red[wave] = ss;
    __syncthreads();
    if (tid == 0) {
        float tot = red[0] + red[1] + red[2] + red[3];
        s_inv = 1.0f / sqrtf(tot / (float)H_ + EPS_);
    }
    __syncthreads();
    float inv = s_inv;

    float4 sv = ((const float4*)scale)[tid];
    float nv[4];
    nv[0] = xv.x*inv*sv.x; nv[1] = xv.y*inv*sv.y;
    nv[2] = xv.z*inv*sv.z; nv[3] = xv.w*inv*sv.w;
    ushort4 nb;
    nb.x = f2bf(nv[0]); nb.y = f2bf(nv[1]); nb.z = f2bf(nv[2]); nb.w = f2bf(nv[3]);
    ((ushort4*)(normed_bf + (size_t)t * H_))[tid] = nb;

    float p[E_];
    #pragma unroll
    for (int e = 0; e < E_; e++) p[e] = 0.f;
    int h0 = tid * 4;
    #pragma unroll
    for (int j = 0; j < 4; j++) {
        const float4* g4 = (const float4*)(gk + (size_t)(h0 + j) * E_);
        float4 a = g4[0], b = g4[1];
        float n = nv[j];
        p[0] += n*a.x; p[1] += n*a.y; p[2] += n*a.z; p[3] += n*a.w;
        p[4] += n*b.x; p[5] += n*b.y; p[6] += n*b.z; p[7] += n*b.w;
    }
    __shared__ float pr[E_][4];
    #pragma unroll
    for (int e = 0; e < E_; e++) {
        float v = p[e];
        #pragma unroll
        for (int off = 32; off; off >>= 1) v += __shfl_down(v, off);
        if (lane == 0) pr[e][wave] = v;
    }
    __syncthreads();
    if (tid == 0) {
        float lg[E_];
        #pragma unroll
        for (int e = 0; e < E_; e++)
            lg[e] = pr[e][0] + pr[e][1] + pr[e][2] + pr[e][3] + gb[e];
        int b0 = -1, b1 = -1; float l0 = -1e30f, l1 = -1e30f;
        #pragma unroll
        for (int e = 0; e < E_; e++) {
            if (lg[e] > l0) { l1 = l0; b1 = b0; l0 = lg[e]; b0 = e; }
            else if (lg[e] > l1) { l1 = lg[e]; b1 = e; }
        }
        float e1 = expf(l1 - l0);
        float w0 = 1.f / (1.f + e1);
        float w1 = e1 / (1.f + e1);
        int p0 = atomicAdd(&counts[b0], 1);
        tok_list[b0 * T_ + p0] = t * 2 + 0; w_list[b0 * T_ + p0] = w0;
        int p1 = atomicAdd(&counts[b1], 1);
        tok_list[b1 * T_ + p1] = t * 2 + 1; w_list[b1 * T_ + p1] = w1;
    }
}

// ---------------- Kernel 2: out = x (residual init) ------------------------
__global__ __launch_bounds__(256) void k_init_out(
    const float* __restrict__ x, float* __restrict__ out)
{
    size_t i = (size_t)blockIdx.x * 256 + threadIdx.x;
    ((float4*)out)[i] = ((const float4*)x)[i];
}

// ---------------- Kernel 3: GEMM1 128x128x64 + SwiGLU -> act ---------------
// N-tile = 64 gate features + 64 linear features (same i range).
// Wave grid 2x2: wc=0 -> gate cols, wc=1 -> linear cols; epilogue exchanges
// half of each accumulator through LDS so both waves write act rows.
template<bool PRE>
__global__ __launch_bounds__(256) void k_mlp1(
    const float* __restrict__ w1f, const unsigned short* __restrict__ w1b,
    const float* __restrict__ b1,
    const unsigned short* __restrict__ normed_bf,
    const int* __restrict__ counts, const int* __restrict__ tok_list,
    unsigned short* __restrict__ act)
{
    int e = blockIdx.z;
    int Ne = counts[e];
    int mt0 = blockIdx.y * 128;
    if (mt0 >= Ne) return;
    int it0 = blockIdx.x * 64;

    int tid = threadIdx.x;
    int w = tid >> 6, lane = tid & 63;
    int quad = lane >> 4, m16 = lane & 15;
    int wr = w >> 1, wc = w & 1;

    __shared__ __align__(16) char smem[35840];
    unsigned short* lA = (unsigned short*)smem;            // 16 KB (128x64)
    unsigned short* lB = (unsigned short*)(smem + 16384);  // 16 KB
    __shared__ int ls_tk[128];

    if (tid < 128) {
        int slot = mt0 + tid;
        ls_tk[tid] = (slot < Ne) ? tok_list[e * T_ + slot] : -1;
    }
    __syncthreads();

    // staging sources: each wave stages rows [w*32, w*32+32) of A and B
    int rsub = lane >> 3, jj = lane & 7;
    const unsigned short* srcA[4];
    const unsigned short* srcB[4];   // PRE path
    const float* srcBf[4];           // fallback path
    int rowB[4];
    #pragma unroll
    for (int c = 0; c < 4; c++) {
        int r = w * 32 + c * 8 + rsub;
        int j = jj ^ (r & 7);
        int tk = ls_tk[r];
        int tok = (tk < 0) ? 0 : (tk >> 1);
        srcA[c] = normed_bf + (size_t)tok * H_ + j * 8;
        int feat = (r < 64) ? (it0 + r) : (I_ + it0 + r - 64);
        rowB[c] = feat;
        if (PRE) srcB[c] = w1b + (size_t)e * 2 * I_ * H_ + (size_t)feat * H_ + j * 8;
    }
    // fallback B staging mapping: thread -> (row, half)
    int rF = tid >> 1, halfF = tid & 1;
    int featF = (rF < 64) ? (it0 + rF) : (I_ + it0 + rF - 64);
    if (!PRE) srcBf[0] = w1f + (size_t)e * 2 * I_ * H_ + (size_t)featF * H_ + halfF * 32;

    // fragment read offsets (elems), fixed for all iters
    int aoff[2][4], boff[2][4];
    #pragma unroll
    for (int ks2 = 0; ks2 < 2; ks2++) {
        #pragma unroll
        for (int i4 = 0; i4 < 4; i4++) {
            int j = ks2 * 4 + quad;
            int rA = wr * 64 + i4 * 16 + m16;
            aoff[ks2][i4] = rA * 64 + ((j ^ (rA & 7)) * 8);
            int rB = wc * 64 + i4 * 16 + m16;
            boff[ks2][i4] = rB * 64 + ((j ^ (rB & 7)) * 8);
        }
    }

    f32x4 acc[4][4];
    #pragma unroll
    for (int mi = 0; mi < 4; mi++)
        #pragma unroll
        for (int ni = 0; ni < 4; ni++)
            acc[mi][ni] = (f32x4){0.f, 0.f, 0.f, 0.f};

    for (int kk = 0; kk < H_; kk += 64) {
        #pragma unroll
        for (int c = 0; c < 4; c++) {
            gl_lds16(srcA[c], lA + (w * 32 + c * 8) * 64);
            srcA[c] += 64;
        }
        if (PRE) {
            #pragma unroll
            for (int c = 0; c < 4; c++) {
                gl_lds16(srcB[c], lB + (w * 32 + c * 8) * 64);
                srcB[c] += 64;
            }
        } else {
            const float* s = srcBf[0] + kk;
            #pragma unroll
            for (int q = 0; q < 4; q++) {
                float4 f0 = ((const float4*)s)[q * 2];
                float4 f1 = ((const float4*)s)[q * 2 + 1];
                ushort4 u0, u1;
                u0.x = f2bf(f0.x); u0.y = f2bf(f0.y); u0.z = f2bf(f0.z); u0.w = f2bf(f0.w);
                u1.x = f2bf(f1.x); u1.y = f2bf(f1.y); u1.z = f2bf(f1.z); u1.w = f2bf(f1.w);
                int j = (halfF * 4 + q) ^ (rF & 7);
                *(ushort4*)(lB + rF * 64 + j * 8)     = u0;
                *(ushort4*)(lB + rF * 64 + j * 8 + 4) = u1;
            }
        }
        __syncthreads();
        #pragma unroll
        for (int ks2 = 0; ks2 < 2; ks2++) {
            bf16x8 av[4], bv[4];
            #pragma unroll
            for (int i4 = 0; i4 < 4; i4++) av[i4] = *(const bf16x8*)(lA + aoff[ks2][i4]);
            #pragma unroll
            for (int i4 = 0; i4 < 4; i4++) bv[i4] = *(const bf16x8*)(lB + boff[ks2][i4]);
            #pragma unroll
            for (int mi = 0; mi < 4; mi++)
                #pragma unroll
                for (int ni = 0; ni < 4; ni++)
                    acc[mi][ni] = __builtin_amdgcn_mfma_f32_16x16x32_bf16(
                        av[mi], bv[ni], acc[mi][ni], 0, 0, 0);
        }
        __syncthreads();
    }

    // ---- epilogue: balanced gate/linear exchange through LDS ----
    float* exL = (float*)smem;          // [2][2][4][4][68]
    float* exG = exL + 4352;
    const float* b1g = b1 + (size_t)e * 2 * I_;
    const float* b1l = b1g + I_;

    #pragma unroll
    for (int mih = 0; mih < 2; mih++) {
        #pragma unroll
        for (int ni = 0; ni < 4; ni++) {
            #pragma unroll
            for (int reg = 0; reg < 4; reg++) {
                int ix = (((wr * 2 + mih) * 4 + ni) * 4 + reg) * 68 + quad * 17 + m16;
                if (wc == 1) exL[ix] = acc[mih][ni][reg];       // linear sends lo half
                else         exG[ix] = acc[2 + mih][ni][reg];   // gate sends hi half
            }
        }
    }
    __syncthreads();

    int miBase = (wc == 0) ? 0 : 2;
    #pragma unroll
    for (int mih = 0; mih < 2; mih++) {
        int mi = miBase + mih;
        #pragma unroll
        for (int reg = 0; reg < 4; reg++) {
            int row = wr * 64 + mi * 16 + quad * 4 + reg;
            int tk = ls_tk[row];
            if (tk < 0) continue;
            #pragma unroll
            for (int ni = 0; ni < 4; ni++) {
                int i = it0 + ni * 16 + m16;
                int ix = (((wr * 2 + mih) * 4 + ni) * 4 + reg) * 68 + quad * 17 + m16;
                float g, l;
                if (wc == 0) { g = acc[mi][ni][reg]; l = exL[ix]; }
                else         { g = exG[ix];          l = acc[mi][ni][reg]; }
                g += b1g[i]; l += b1l[i];
                g = fminf(g, 7.f);
                l = fminf(fmaxf(l, -7.f), 7.f);
                float sw = g / (1.f + expf(-1.702f * g));
                act[(size_t)tk * I_ + i] = f2bf(sw * (l + 1.f));
            }
        }
    }
}

// ---------------- Kernel 4: GEMM2 128x128x64, weighted scatter-add ---------
template<bool PRE>
__global__ __launch_bounds__(256) void k_mlp2(
    const float* __restrict__ w2f, const unsigned short* __restrict__ w2b,
    const float* __restrict__ b2,
    const unsigned short* __restrict__ act,
    const int* __restrict__ counts, const int* __restrict__ tok_list,
    const float* __restrict__ w_list,
    float* __restrict__ out)
{
    int e = blockIdx.z;
    int Ne = counts[e];
    int mt0 = blockIdx.y * 128;
    if (mt0 >= Ne) return;
    int ht0 = blockIdx.x * 128;

    int tid = threadIdx.x;
    int w = tid >> 6, lane = tid & 63;
    int quad = lane >> 4, m16 = lane & 15;
    int wr = w >> 1, wc = w & 1;

    __shared__ __align__(16) char smem[32768];
    unsigned short* lA = (unsigned short*)smem;
    unsigned short* lB = (unsigned short*)(smem + 16384);
    __shared__ int ls_tk[128];
    __shared__ float ls_w[128];

    if (tid < 128) {
        int slot = mt0 + tid;
        ls_tk[tid] = (slot < Ne) ? tok_list[e * T_ + slot] : -1;
        ls_w[tid]  = (slot < Ne) ? w_list[e * T_ + slot] : 0.f;
    }
    __syncthreads();

    int rsub = lane >> 3, jj = lane & 7;
    const unsigned short* srcA[4];
    const unsigned short* srcB[4];
    const float* srcBf0 = nullptr;
    #pragma unroll
    for (int c = 0; c < 4; c++) {
        int r = w * 32 + c * 8 + rsub;
        int j = jj ^ (r & 7);
        int tk = ls_tk[r];
        int tka = (tk < 0) ? 0 : tk;
        srcA[c] = act + (size_t)tka * I_ + j * 8;
        if (PRE) srcB[c] = w2b + (size_t)e * H_ * I_ + (size_t)(ht0 + r) * I_ + j * 8;
    }
    int rF = tid >> 1, halfF = tid & 1;
    if (!PRE) srcBf0 = w2f + (size_t)e * H_ * I_ + (size_t)(ht0 + rF) * I_ + halfF * 32;

    int aoff[2][4], boff[2][4];
    #pragma unroll
    for (int ks2 = 0; ks2 < 2; ks2++) {
        #pragma unroll
        for (int i4 = 0; i4 < 4; i4++) {
            int j = ks2 * 4 + quad;
            int rA = wr * 64 + i4 * 16 + m16;
            aoff[ks2][i4] = rA * 64 + ((j ^ (rA & 7)) * 8);
            int rB = wc * 64 + i4 * 16 + m16;
            boff[ks2][i4] = rB * 64 + ((j ^ (rB & 7)) * 8);
        }
    }

    f32x4 acc[4][4];
    #pragma unroll
    for (int mi = 0; mi < 4; mi++)
        #pragma unroll
        for (int ni = 0; ni < 4; ni++)
            acc[mi][ni] = (f32x4){0.f, 0.f, 0.f, 0.f};

    for (int kk = 0; kk < I_; kk += 64) {
        #pragma unroll
        for (int c = 0; c < 4; c++) {
            gl_lds16(srcA[c], lA + (w * 32 + c * 8) * 64);
            srcA[c] += 64;
        }
        if (PRE) {
            #pragma unroll
            for (int c = 0; c < 4; c++) {
                gl_lds16(srcB[c], lB + (w * 32 + c * 8) * 64);
                srcB[c] += 64;
            }
        } else {
            const float* s = srcBf0 + kk;
            #pragma unroll
            for (int q = 0; q < 4; q++) {
                float4 f0 = ((const float4*)s)[q * 2];
                float4 f1 = ((const float4*)s)[q * 2 + 1];
                ushort4 u0, u1;
                u0.x = f2bf(f0.x); u0.y = f2bf(f0.y); u0.z = f2bf(f0.z); u0.w = f2bf(f0.w);
                u1.x = f2bf(f1.x); u1.y = f2bf(f1.y); u1.z = f2bf(f1.z); u1.w = f2bf(f1.w);
                int j = (halfF * 4 + q) ^ (rF & 7);
                *(ushort4*)(lB + rF * 64 + j * 8)     = u0;
                *(ushort4*)(lB + rF * 64 + j * 8 + 4) = u1;
            }
        }
        __syncthreads();
        #pragma unroll
        for (int ks2 = 0; ks2 < 2; ks2++) {
            bf16x8 av[4], bv[4];
            #pragma unroll
            for (int i4 = 0; i4 < 4; i4++) av[i4] = *(const bf16x8*)(lA + aoff[ks2][i4]);
            #pragma unroll
            for (int i4 = 0; i4 < 4; i4++) bv[i4] = *(const bf16x8*)(lB + boff[ks2][i4]);
            #pragma unroll
            for (int mi = 0; mi < 4; mi++)
                #pragma unroll
                for (int ni = 0; ni < 4; ni++)
                    acc[mi][ni] = __builtin_amdgcn_mfma_f32_16x16x32_bf16(
                        av[mi], bv[ni], acc[mi][ni], 0, 0, 0);
        }
        __syncthreads();
    }

    const float* b2e = b2 + (size_t)e * H_;
    #pragma unroll
    for (int mi = 0; mi < 4; mi++) {
        #pragma unroll
        for (int reg = 0; reg < 4; reg++) {
            int row = wr * 64 + mi * 16 + quad * 4 + reg;
            int tk = ls_tk[row];
            if (tk < 0) continue;
            int t = tk >> 1;
            float wgt = ls_w[row];
            #pragma unroll
            for (int ni = 0; ni < 4; ni++) {
                int h = ht0 + wc * 64 + ni * 16 + m16;
                float v = acc[mi][ni][reg] + b2e[h];
                atomicAdd(&out[(size_t)t * H_ + h], wgt * v);
            }
        }
    }
}

// ---------------- launcher -------------------------------------------------
extern "C" void kernel_launch(void* const* d_in, const int* in_sizes, int n_in,
                              void* d_out, int out_size, void* d_ws, size_t ws_size,
                              hipStream_t stream) {
    const float* x     = (const float*)d_in[0];
    const float* scale = (const float*)d_in[1];
    const float* gk    = (const float*)d_in[2];
    const float* gb    = (const float*)d_in[3];
    const float* w1    = (const float*)d_in[4];
    const float* b1    = (const float*)d_in[5];
    const float* w2    = (const float*)d_in[6];
    const float* b2    = (const float*)d_in[7];
    float* out = (float*)d_out;

    char* ws = (char*)d_ws;
    const size_t MB = 1024 * 1024;
    bool pre = ws_size >= (size_t)138 * MB;

    unsigned short* normed_bf = (unsigned short*)ws;                    // 8 MB
    unsigned short* act       = (unsigned short*)(ws + 8 * MB);         // 32 MB
    unsigned short* w1b = nullptr;
    unsigned short* w2b = nullptr;
    char* ctl;
    if (pre) {
        w1b = (unsigned short*)(ws + 40 * MB);    // 64 MB
        w2b = (unsigned short*)(ws + 104 * MB);   // 32 MB
        ctl = ws + 136 * MB;
    } else {
        ctl = ws + 40 * MB;
    }
    int*   counts   = (int*)ctl;
    int*   tok_list = (int*)(ctl + 256);
    float* w_list   = (float*)(ctl + 256 + (size_t)E_ * T_ * 4);

    hipMemsetAsync(counts, 0, E_ * sizeof(int), stream);

    k_norm_gate<<<dim3(T_), dim3(256), 0, stream>>>(x, scale, gk, gb,
                                                    normed_bf, counts, tok_list, w_list);
    if (pre) {
        k_convert<<<dim3((E_ * 2 * I_ * H_) / (256 * 8)), dim3(256), 0, stream>>>(w1, w1b);
        k_convert<<<dim3((E_ * H_ * I_) / (256 * 8), 1, 1), dim3(256), 0, stream>>>(w2, w2b);
    }
    k_init_out<<<dim3(T_ * H_ / (256 * 4)), dim3(256), 0, stream>>>(x, out);

    if (pre) {
        k_mlp1<true><<<dim3(I_ / 64, T_ / 128, E_), dim3(256), 0, stream>>>(
            nullptr, w1b, b1, normed_bf, counts, tok_list, act);
        k_mlp2<true><<<dim3(H_ / 128, T_ / 128, E_), dim3(256), 0, stream>>>(
            nullptr, w2b, b2, act, counts, tok_list, w_list, out);
    } else {
        k_mlp1<false><<<dim3(I_ / 64, T_ / 128, E_), dim3(256), 0, stream>>>(
            w1, nullptr, b1, normed_bf, counts, tok_list, act);
        k_mlp2<false><<<dim3(H_ / 128, T_ / 128, E_), dim3(256), 0, stream>>>(
            w2, nullptr, b2, act, counts, tok_list, w_list, out);
    }
}

// Round 3
// 1013.175 us; speedup vs baseline: 1.0026x; 1.0026x over previous
//
#include <hip/hip_runtime.h>
#include <hip/hip_bf16.h>
#include <math.h>

#define T_ 4096
#define H_ 1024
#define E_ 8
#define I_ 2048
#define EPS_ 1e-5f

using bf16x8 = __attribute__((ext_vector_type(8))) short;
using f32x4  = __attribute__((ext_vector_type(4))) float;

static __device__ __forceinline__ unsigned short f2bf(float f) {
    union { float f; unsigned int u; } v; v.f = f;
    unsigned int u = v.u;
    u += 0x7fffu + ((u >> 16) & 1u);   // RNE
    return (unsigned short)(u >> 16);
}

static __device__ __forceinline__ void gl_lds16(const void* g, void* l) {
    __builtin_amdgcn_global_load_lds(
        (const __attribute__((address_space(1))) unsigned int*)g,
        (__attribute__((address_space(3))) unsigned int*)l, 16, 0, 0);
}

// ---------------- Kernel 0: fp32 -> bf16 weight preconvert -----------------
__global__ __launch_bounds__(256) void k_convert(
    const float* __restrict__ src, unsigned short* __restrict__ dst)
{
    size_t i = (size_t)blockIdx.x * 256 + threadIdx.x;
    const float4* s = (const float4*)src + i * 2;
    float4 a = s[0], b = s[1];
    ushort4 lo, hi;
    lo.x = f2bf(a.x); lo.y = f2bf(a.y); lo.z = f2bf(a.z); lo.w = f2bf(a.w);
    hi.x = f2bf(b.x); hi.y = f2bf(b.y); hi.z = f2bf(b.z); hi.w = f2bf(b.w);
    ((ushort4*)dst)[i * 2]     = lo;
    ((ushort4*)dst)[i * 2 + 1] = hi;
}

// ---------------- Kernel 1: RMSNorm + gate logits + top-2 routing ----------
__global__ __launch_bounds__(256) void k_norm_gate(
    const float* __restrict__ x, const float* __restrict__ scale,
    const float* __restrict__ gk, const float* __restrict__ gb,
    unsigned short* __restrict__ normed_bf,
    int* __restrict__ counts, int* __restrict__ tok_list, float* __restrict__ w_list)
{
    int t = blockIdx.x;
    int tid = threadIdx.x;
    int lane = tid & 63, wave = tid >> 6;

    float4 xv = ((const float4*)(x + (size_t)t * H_))[tid];
    float ss = xv.x*xv.x + xv.y*xv.y + xv.z*xv.z + xv.w*xv.w;
    #pragma unroll
    for (int off = 32; off; off >>= 1) ss += __shfl_down(ss, off);

    __shared__ float red[4];
    __shared__ float s_inv;
    if (lane == 0) red[wave] = ss;
    __syncthreads();
    if (tid == 0) {
        float tot = red[0] + red[1] + red[2] + red[3];
        s_inv = 1.0f / sqrtf(tot / (float)H_ + EPS_);
    }
    __syncthreads();
    float inv = s_inv;

    float4 sv = ((const float4*)scale)[tid];
    float nv[4];
    nv[0] = xv.x*inv*sv.x; nv[1] = xv.y*inv*sv.y;
    nv[2] = xv.z*inv*sv.z; nv[3] = xv.w*inv*sv.w;
    ushort4 nb;
    nb.x = f2bf(nv[0]); nb.y = f2bf(nv[1]); nb.z = f2bf(nv[2]); nb.w = f2bf(nv[3]);
    ((ushort4*)(normed_bf + (size_t)t * H_))[tid] = nb;

    float p[E_];
    #pragma unroll
    for (int e = 0; e < E_; e++) p[e] = 0.f;
    int h0 = tid * 4;
    #pragma unroll
    for (int j = 0; j < 4; j++) {
        const float4* g4 = (const float4*)(gk + (size_t)(h0 + j) * E_);
        float4 a = g4[0], b = g4[1];
        float n = nv[j];
        p[0] += n*a.x; p[1] += n*a.y; p[2] += n*a.z; p[3] += n*a.w;
        p[4] += n*b.x; p[5] += n*b.y; p[6] += n*b.z; p[7] += n*b.w;
    }
    __shared__ float pr[E_][4];
    #pragma unroll
    for (int e = 0; e < E_; e++) {
        float v = p[e];
        #pragma unroll
        for (int off = 32; off; off >>= 1) v += __shfl_down(v, off);
        if (lane == 0) pr[e][wave] = v;
    }
    __syncthreads();
    if (tid == 0) {
        float lg[E_];
        #pragma unroll
        for (int e = 0; e < E_; e++)
            lg[e] = pr[e][0] + pr[e][1] + pr[e][2] + pr[e][3] + gb[e];
        int b0 = -1, b1 = -1; float l0 = -1e30f, l1 = -1e30f;
        #pragma unroll
        for (int e = 0; e < E_; e++) {
            if (lg[e] > l0) { l1 = l0; b1 = b0; l0 = lg[e]; b0 = e; }
            else if (lg[e] > l1) { l1 = lg[e]; b1 = e; }
        }
        float e1 = expf(l1 - l0);
        float w0 = 1.f / (1.f + e1);
        float w1 = e1 / (1.f + e1);
        int p0 = atomicAdd(&counts[b0], 1);
        tok_list[b0 * T_ + p0] = t * 2 + 0; w_list[b0 * T_ + p0] = w0;
        int p1 = atomicAdd(&counts[b1], 1);
        tok_list[b1 * T_ + p1] = t * 2 + 1; w_list[b1 * T_ + p1] = w1;
    }
}

// ---------------- Kernel 2: out = x (residual init) ------------------------
__global__ __launch_bounds__(256) void k_init_out(
    const float* __restrict__ x, float* __restrict__ out)
{
    size_t i = (size_t)blockIdx.x * 256 + threadIdx.x;
    ((float4*)out)[i] = ((const float4*)x)[i];
}

// ---------------- Kernel 3: GEMM1 128x(64+64)x64 + SwiGLU -> act -----------
template<bool PRE>
__global__ __launch_bounds__(256, 1) void k_mlp1(
    const float* __restrict__ w1f, const unsigned short* __restrict__ w1b,
    const float* __restrict__ b1,
    const unsigned short* __restrict__ normed_bf,
    const int* __restrict__ counts, const int* __restrict__ tok_list,
    unsigned short* __restrict__ act)
{
    int e = blockIdx.z;
    int Ne = counts[e];
    int mt0 = blockIdx.y * 128;
    if (mt0 >= Ne) return;
    int it0 = blockIdx.x * 64;

    int tid = threadIdx.x;
    int w = tid >> 6, lane = tid & 63;
    int quad = lane >> 4, m16 = lane & 15;
    int wr = w >> 1, wc = w & 1;

    __shared__ __align__(16) char smem[35840];
    unsigned short* lA = (unsigned short*)smem;            // 16 KB (128x64)
    unsigned short* lB = (unsigned short*)(smem + 16384);  // 16 KB
    __shared__ int ls_tk[128];

    if (tid < 128) {
        int slot = mt0 + tid;
        ls_tk[tid] = (slot < Ne) ? tok_list[e * T_ + slot] : -1;
    }
    __syncthreads();

    // staging geometry: wave w stages rows [w*32, w*32+32); lane = (rsub, jj)
    int rsub = lane >> 3, jj = lane & 7;
    int jsw = (jj ^ rsub) * 8;         // XOR-swizzled source column (elems); r&7 == rsub
    const unsigned short* sA[4];
    #pragma unroll
    for (int c = 0; c < 4; c++) {
        int r = w * 32 + c * 8 + rsub;
        int tk = ls_tk[r];
        int tok = (tk < 0) ? 0 : (tk >> 1);
        sA[c] = normed_bf + (size_t)tok * H_ + jsw;
    }
    // B rows: [0,64)=gate feats it0.., [64,128)=linear feats I_+it0..
    int featBase = (w < 2) ? (it0 + w * 32) : (I_ + it0 + (w - 2) * 32);
    const unsigned short* sB0 = PRE
        ? (w1b + (size_t)e * 2 * I_ * H_ + (size_t)(featBase + rsub) * H_ + jsw)
        : nullptr;

    int rF = tid >> 1, halfF = tid & 1;
    const float* sBf0 = nullptr;
    if (!PRE) {
        int featF = (rF < 64) ? (it0 + rF) : (I_ + it0 + rF - 64);
        sBf0 = w1f + (size_t)e * 2 * I_ * H_ + (size_t)featF * H_ + halfF * 32;
    }

    f32x4 acc[4][4];
    #pragma unroll
    for (int mi = 0; mi < 4; mi++)
        #pragma unroll
        for (int ni = 0; ni < 4; ni++)
            acc[mi][ni] = (f32x4){0.f, 0.f, 0.f, 0.f};

    for (int kk = 0; kk < H_; kk += 64) {
        #pragma unroll
        for (int c = 0; c < 4; c++)
            gl_lds16(sA[c] + kk, lA + (w * 32 + c * 8) * 64);
        if (PRE) {
            #pragma unroll
            for (int c = 0; c < 4; c++)
                gl_lds16(sB0 + (size_t)c * 8 * H_ + kk, lB + (w * 32 + c * 8) * 64);
        } else {
            const float* s = sBf0 + kk;
            #pragma unroll
            for (int q = 0; q < 4; q++) {
                float4 f0 = ((const float4*)s)[q * 2];
                float4 f1 = ((const float4*)s)[q * 2 + 1];
                ushort4 u0, u1;
                u0.x = f2bf(f0.x); u0.y = f2bf(f0.y); u0.z = f2bf(f0.z); u0.w = f2bf(f0.w);
                u1.x = f2bf(f1.x); u1.y = f2bf(f1.y); u1.z = f2bf(f1.z); u1.w = f2bf(f1.w);
                int j = (halfF * 4 + q) ^ (rF & 7);
                *(ushort4*)(lB + rF * 64 + j * 8)     = u0;
                *(ushort4*)(lB + rF * 64 + j * 8 + 4) = u1;
            }
        }
        __syncthreads();
        #pragma unroll
        for (int ks2 = 0; ks2 < 2; ks2++) {
            int col = ((ks2 * 4 + quad) ^ (m16 & 7)) * 8;   // rowA&7 == rowB&7 == m16&7
            const unsigned short* pA = lA + (wr * 64 + m16) * 64 + col;
            const unsigned short* pB = lB + (wc * 64 + m16) * 64 + col;
            bf16x8 av[4], bv[4];
            #pragma unroll
            for (int i4 = 0; i4 < 4; i4++) av[i4] = *(const bf16x8*)(pA + i4 * 1024);
            #pragma unroll
            for (int i4 = 0; i4 < 4; i4++) bv[i4] = *(const bf16x8*)(pB + i4 * 1024);
            #pragma unroll
            for (int mi = 0; mi < 4; mi++)
                #pragma unroll
                for (int ni = 0; ni < 4; ni++)
                    acc[mi][ni] = __builtin_amdgcn_mfma_f32_16x16x32_bf16(
                        av[mi], bv[ni], acc[mi][ni], 0, 0, 0);
        }
        __syncthreads();
    }

    // ---- epilogue: balanced gate/linear exchange through LDS ----
    float* exL = (float*)smem;          // [2][2][4][4][68]
    float* exG = exL + 4352;
    const float* b1g = b1 + (size_t)e * 2 * I_;
    const float* b1l = b1g + I_;

    #pragma unroll
    for (int mih = 0; mih < 2; mih++) {
        #pragma unroll
        for (int ni = 0; ni < 4; ni++) {
            #pragma unroll
            for (int reg = 0; reg < 4; reg++) {
                int ix = (((wr * 2 + mih) * 4 + ni) * 4 + reg) * 68 + quad * 17 + m16;
                if (wc == 1) exL[ix] = acc[mih][ni][reg];       // linear sends lo half
                else         exG[ix] = acc[2 + mih][ni][reg];   // gate sends hi half
            }
        }
    }
    __syncthreads();

    int miBase = (wc == 0) ? 0 : 2;
    #pragma unroll
    for (int mih = 0; mih < 2; mih++) {
        int mi = miBase + mih;
        #pragma unroll
        for (int reg = 0; reg < 4; reg++) {
            int row = wr * 64 + mi * 16 + quad * 4 + reg;
            int tk = ls_tk[row];
            if (tk < 0) continue;
            #pragma unroll
            for (int ni = 0; ni < 4; ni++) {
                int i = it0 + ni * 16 + m16;
                int ix = (((wr * 2 + mih) * 4 + ni) * 4 + reg) * 68 + quad * 17 + m16;
                float g, l;
                if (wc == 0) { g = acc[mi][ni][reg]; l = exL[ix]; }
                else         { g = exG[ix];          l = acc[mi][ni][reg]; }
                g += b1g[i]; l += b1l[i];
                g = fminf(g, 7.f);
                l = fminf(fmaxf(l, -7.f), 7.f);
                float sw = g / (1.f + expf(-1.702f * g));
                act[(size_t)tk * I_ + i] = f2bf(sw * (l + 1.f));
            }
        }
    }
}

// ---------------- Kernel 4: GEMM2 128x128, weighted scatter-add ------------
template<bool PRE>
__global__ __launch_bounds__(256, 1) void k_mlp2(
    const float* __restrict__ w2f, const unsigned short* __restrict__ w2b,
    const float* __restrict__ b2,
    const unsigned short* __restrict__ act,
    const int* __restrict__ counts, const int* __restrict__ tok_list,
    const float* __restrict__ w_list,
    float* __restrict__ out)
{
    int e = blockIdx.z;
    int Ne = counts[e];
    int mt0 = blockIdx.y * 128;
    if (mt0 >= Ne) return;
    int ht0 = blockIdx.x * 128;

    int tid = threadIdx.x;
    int w = tid >> 6, lane = tid & 63;
    int quad = lane >> 4, m16 = lane & 15;
    int wr = w >> 1, wc = w & 1;

    __shared__ __align__(16) char smem[32768];
    unsigned short* lA = (unsigned short*)smem;
    unsigned short* lB = (unsigned short*)(smem + 16384);
    __shared__ int ls_tk[128];
    __shared__ float ls_w[128];

    if (tid < 128) {
        int slot = mt0 + tid;
        ls_tk[tid] = (slot < Ne) ? tok_list[e * T_ + slot] : -1;
        ls_w[tid]  = (slot < Ne) ? w_list[e * T_ + slot] : 0.f;
    }
    __syncthreads();

    int rsub = lane >> 3, jj = lane & 7;
    int jsw = (jj ^ rsub) * 8;
    const unsigned short* sA[4];
    #pragma unroll
    for (int c = 0; c < 4; c++) {
        int r = w * 32 + c * 8 + rsub;
        int tk = ls_tk[r];
        int tka = (tk < 0) ? 0 : tk;
        sA[c] = act + (size_t)tka * I_ + jsw;
    }
    const unsigned short* sB0 = PRE
        ? (w2b + (size_t)e * H_ * I_ + (size_t)(ht0 + w * 32 + rsub) * I_ + jsw)
        : nullptr;

    int rF = tid >> 1, halfF = tid & 1;
    const float* sBf0 = nullptr;
    if (!PRE)
        sBf0 = w2f + (size_t)e * H_ * I_ + (size_t)(ht0 + rF) * I_ + halfF * 32;

    f32x4 acc[4][4];
    #pragma unroll
    for (int mi = 0; mi < 4; mi++)
        #pragma unroll
        for (int ni = 0; ni < 4; ni++)
            acc[mi][ni] = (f32x4){0.f, 0.f, 0.f, 0.f};

    for (int kk = 0; kk < I_; kk += 64) {
        #pragma unroll
        for (int c = 0; c < 4; c++)
            gl_lds16(sA[c] + kk, lA + (w * 32 + c * 8) * 64);
        if (PRE) {
            #pragma unroll
            for (int c = 0; c < 4; c++)
                gl_lds16(sB0 + (size_t)c * 8 * I_ + kk, lB + (w * 32 + c * 8) * 64);
        } else {
            const float* s = sBf0 + kk;
            #pragma unroll
            for (int q = 0; q < 4; q++) {
                float4 f0 = ((const float4*)s)[q * 2];
                float4 f1 = ((const float4*)s)[q * 2 + 1];
                ushort4 u0, u1;
                u0.x = f2bf(f0.x); u0.y = f2bf(f0.y); u0.z = f2bf(f0.z); u0.w = f2bf(f0.w);
                u1.x = f2bf(f1.x); u1.y = f2bf(f1.y); u1.z = f2bf(f1.z); u1.w = f2bf(f1.w);
                int j = (halfF * 4 + q) ^ (rF & 7);
                *(ushort4*)(lB + rF * 64 + j * 8)     = u0;
                *(ushort4*)(lB + rF * 64 + j * 8 + 4) = u1;
            }
        }
        __syncthreads();
        #pragma unroll
        for (int ks2 = 0; ks2 < 2; ks2++) {
            int col = ((ks2 * 4 + quad) ^ (m16 & 7)) * 8;
            const unsigned short* pA = lA + (wr * 64 + m16) * 64 + col;
            const unsigned short* pB = lB + (wc * 64 + m16) * 64 + col;
            bf16x8 av[4], bv[4];
            #pragma unroll
            for (int i4 = 0; i4 < 4; i4++) av[i4] = *(const bf16x8*)(pA + i4 * 1024);
            #pragma unroll
            for (int i4 = 0; i4 < 4; i4++) bv[i4] = *(const bf16x8*)(pB + i4 * 1024);
            #pragma unroll
            for (int mi = 0; mi < 4; mi++)
                #pragma unroll
                for (int ni = 0; ni < 4; ni++)
                    acc[mi][ni] = __builtin_amdgcn_mfma_f32_16x16x32_bf16(
                        av[mi], bv[ni], acc[mi][ni], 0, 0, 0);
        }
        __syncthreads();
    }

    const float* b2e = b2 + (size_t)e * H_;
    #pragma unroll
    for (int mi = 0; mi < 4; mi++) {
        #pragma unroll
        for (int reg = 0; reg < 4; reg++) {
            int row = wr * 64 + mi * 16 + quad * 4 + reg;
            int tk = ls_tk[row];
            if (tk < 0) continue;
            int t = tk >> 1;
            float wgt = ls_w[row];
            #pragma unroll
            for (int ni = 0; ni < 4; ni++) {
                int h = ht0 + wc * 64 + ni * 16 + m16;
                float v = acc[mi][ni][reg] + b2e[h];
                atomicAdd(&out[(size_t)t * H_ + h], wgt * v);
            }
        }
    }
}

// ---------------- launcher -------------------------------------------------
extern "C" void kernel_launch(void* const* d_in, const int* in_sizes, int n_in,
                              void* d_out, int out_size, void* d_ws, size_t ws_size,
                              hipStream_t stream) {
    const float* x     = (const float*)d_in[0];
    const float* scale = (const float*)d_in[1];
    const float* gk    = (const float*)d_in[2];
    const float* gb    = (const float*)d_in[3];
    const float* w1    = (const float*)d_in[4];
    const float* b1    = (const float*)d_in[5];
    const float* w2    = (const float*)d_in[6];
    const float* b2    = (const float*)d_in[7];
    float* out = (float*)d_out;

    char* ws = (char*)d_ws;
    const size_t MB = 1024 * 1024;
    bool pre = ws_size >= (size_t)138 * MB;

    unsigned short* normed_bf = (unsigned short*)ws;                    // 8 MB
    unsigned short* act       = (unsigned short*)(ws + 8 * MB);         // 32 MB
    unsigned short* w1b = nullptr;
    unsigned short* w2b = nullptr;
    char* ctl;
    if (pre) {
        w1b = (unsigned short*)(ws + 40 * MB);    // 64 MB
        w2b = (unsigned short*)(ws + 104 * MB);   // 32 MB
        ctl = ws + 136 * MB;
    } else {
        ctl = ws + 40 * MB;
    }
    int*   counts   = (int*)ctl;
    int*   tok_list = (int*)(ctl + 256);
    float* w_list   = (float*)(ctl + 256 + (size_t)E_ * T_ * 4);

    hipMemsetAsync(counts, 0, E_ * sizeof(int), stream);

    k_norm_gate<<<dim3(T_), dim3(256), 0, stream>>>(x, scale, gk, gb,
                                                    normed_bf, counts, tok_list, w_list);
    if (pre) {
        k_convert<<<dim3((E_ * 2 * I_ * H_) / (256 * 8)), dim3(256), 0, stream>>>(w1, w1b);
        k_convert<<<dim3((E_ * H_ * I_) / (256 * 8)), dim3(256), 0, stream>>>(w2, w2b);
    }
    k_init_out<<<dim3(T_ * H_ / (256 * 4)), dim3(256), 0, stream>>>(x, out);

    if (pre) {
        k_mlp1<true><<<dim3(I_ / 64, T_ / 128, E_), dim3(256), 0, stream>>>(
            nullptr, w1b, b1, normed_bf, counts, tok_list, act);
        k_mlp2<true><<<dim3(H_ / 128, T_ / 128, E_), dim3(256), 0, stream>>>(
            nullptr, w2b, b2, act, counts, tok_list, w_list, out);
    } else {
        k_mlp1<false><<<dim3(I_ / 64, T_ / 128, E_), dim3(256), 0, stream>>>(
            w1, nullptr, b1, normed_bf, counts, tok_list, act);
        k_mlp2<false><<<dim3(H_ / 128, T_ / 128, E_), dim3(256), 0, stream>>>(
            w2, nullptr, b2, act, counts, tok_list, w_list, out);
    }
}

// Round 4
// 611.760 us; speedup vs baseline: 1.6605x; 1.6562x over previous
//
#include <hip/hip_runtime.h>
#include <hip/hip_bf16.h>
#include <math.h>

#define T_ 4096
#define H_ 1024
#define E_ 8
#define I_ 2048
#define EPS_ 1e-5f
#define LDST 72   // LDS row stride in bf16 elems (144 B, 16B-aligned)

using bf16x8 = __attribute__((ext_vector_type(8))) short;
using f32x4  = __attribute__((ext_vector_type(4))) float;

static __device__ __forceinline__ unsigned short f2bf(float f) {
    union { float f; unsigned int u; } v; v.f = f;
    unsigned int u = v.u;
    u += 0x7fffu + ((u >> 16) & 1u);   // RNE
    return (unsigned short)(u >> 16);
}

// ---------------- Kernel 0: fp32 -> bf16 weight preconvert -----------------
__global__ __launch_bounds__(256) void k_convert(
    const float* __restrict__ src, unsigned short* __restrict__ dst)
{
    size_t i = (size_t)blockIdx.x * 256 + threadIdx.x;
    const float4* s = (const float4*)src + i * 2;
    float4 a = s[0], b = s[1];
    ushort4 lo, hi;
    lo.x = f2bf(a.x); lo.y = f2bf(a.y); lo.z = f2bf(a.z); lo.w = f2bf(a.w);
    hi.x = f2bf(b.x); hi.y = f2bf(b.y); hi.z = f2bf(b.z); hi.w = f2bf(b.w);
    ((ushort4*)dst)[i * 2]     = lo;
    ((ushort4*)dst)[i * 2 + 1] = hi;
}

// ---------------- Kernel 1: RMSNorm + gate logits + top-2 routing ----------
__global__ __launch_bounds__(256) void k_norm_gate(
    const float* __restrict__ x, const float* __restrict__ scale,
    const float* __restrict__ gk, const float* __restrict__ gb,
    unsigned short* __restrict__ normed_bf,
    int* __restrict__ counts, int* __restrict__ tok_list, float* __restrict__ w_list)
{
    int t = blockIdx.x;
    int tid = threadIdx.x;
    int lane = tid & 63, wave = tid >> 6;

    float4 xv = ((const float4*)(x + (size_t)t * H_))[tid];
    float ss = xv.x*xv.x + xv.y*xv.y + xv.z*xv.z + xv.w*xv.w;
    #pragma unroll
    for (int off = 32; off; off >>= 1) ss += __shfl_down(ss, off);

    __shared__ float red[4];
    __shared__ float s_inv;
    if (lane == 0) red[wave] = ss;
    __syncthreads();
    if (tid == 0) {
        float tot = red[0] + red[1] + red[2] + red[3];
        s_inv = 1.0f / sqrtf(tot / (float)H_ + EPS_);
    }
    __syncthreads();
    float inv = s_inv;

    float4 sv = ((const float4*)scale)[tid];
    float nv[4];
    nv[0] = xv.x*inv*sv.x; nv[1] = xv.y*inv*sv.y;
    nv[2] = xv.z*inv*sv.z; nv[3] = xv.w*inv*sv.w;
    ushort4 nb;
    nb.x = f2bf(nv[0]); nb.y = f2bf(nv[1]); nb.z = f2bf(nv[2]); nb.w = f2bf(nv[3]);
    ((ushort4*)(normed_bf + (size_t)t * H_))[tid] = nb;

    float p[E_];
    #pragma unroll
    for (int e = 0; e < E_; e++) p[e] = 0.f;
    int h0 = tid * 4;
    #pragma unroll
    for (int j = 0; j < 4; j++) {
        const float4* g4 = (const float4*)(gk + (size_t)(h0 + j) * E_);
        float4 a = g4[0], b = g4[1];
        float n = nv[j];
        p[0] += n*a.x; p[1] += n*a.y; p[2] += n*a.z; p[3] += n*a.w;
        p[4] += n*b.x; p[5] += n*b.y; p[6] += n*b.z; p[7] += n*b.w;
    }
    __shared__ float pr[E_][4];
    #pragma unroll
    for (int e = 0; e < E_; e++) {
        float v = p[e];
        #pragma unroll
        for (int off = 32; off; off >>= 1) v += __shfl_down(v, off);
        if (lane == 0) pr[e][wave] = v;
    }
    __syncthreads();
    if (tid == 0) {
        float lg[E_];
        #pragma unroll
        for (int e = 0; e < E_; e++)
            lg[e] = pr[e][0] + pr[e][1] + pr[e][2] + pr[e][3] + gb[e];
        int b0 = -1, b1 = -1; float l0 = -1e30f, l1 = -1e30f;
        #pragma unroll
        for (int e = 0; e < E_; e++) {
            if (lg[e] > l0) { l1 = l0; b1 = b0; l0 = lg[e]; b0 = e; }
            else if (lg[e] > l1) { l1 = lg[e]; b1 = e; }
        }
        float e1 = expf(l1 - l0);
        float w0 = 1.f / (1.f + e1);
        float w1 = e1 / (1.f + e1);
        int p0 = atomicAdd(&counts[b0], 1);
        tok_list[b0 * T_ + p0] = t * 2 + 0; w_list[b0 * T_ + p0] = w0;
        int p1 = atomicAdd(&counts[b1], 1);
        tok_list[b1 * T_ + p1] = t * 2 + 1; w_list[b1 * T_ + p1] = w1;
    }
}

// ---------------- Kernel 2: out = x (residual init) ------------------------
__global__ __launch_bounds__(256) void k_init_out(
    const float* __restrict__ x, float* __restrict__ out)
{
    size_t i = (size_t)blockIdx.x * 256 + threadIdx.x;
    ((float4*)out)[i] = ((const float4*)x)[i];
}

// ---------------- Kernel 3: GEMM1 (normed x W1^T) + SwiGLU -> act ----------
// Tile 64 slots x 64 i (gate + linear tiles). Round-1 proven structure;
// PRE=true loads preconverted bf16 weights (no in-loop convert).
template<bool PRE>
__global__ __launch_bounds__(256) void k_mlp1(
    const float* __restrict__ w1f, const unsigned short* __restrict__ w1b,
    const float* __restrict__ b1,
    const unsigned short* __restrict__ normed_bf,
    const int* __restrict__ counts, const int* __restrict__ tok_list,
    unsigned short* __restrict__ act)
{
    int e = blockIdx.z;
    int Ne = counts[e];
    int mt0 = blockIdx.y * 64;
    if (mt0 >= Ne) return;
    int it0 = blockIdx.x * 64;
    int tid = threadIdx.x;
    int lane = tid & 63, wave = tid >> 6;
    int quad = lane >> 4, m16 = lane & 15;

    __shared__ unsigned short lA[64 * LDST];
    __shared__ unsigned short lBg[64 * LDST];
    __shared__ unsigned short lBl[64 * LDST];
    __shared__ int ls_tk[64];

    if (tid < 64) {
        int slot = mt0 + tid;
        ls_tk[tid] = (slot < Ne) ? tok_list[e * T_ + slot] : -1;
    }
    __syncthreads();

    f32x4 accg[4], accl[4];
    #pragma unroll
    for (int ns = 0; ns < 4; ns++) {
        accg[ns] = (f32x4){0.f, 0.f, 0.f, 0.f};
        accl[ns] = (f32x4){0.f, 0.f, 0.f, 0.f};
    }

    const size_t w1base = (size_t)e * 2 * I_ * H_;
    int rA = tid >> 3, sgA = tid & 7;      // A: 8 threads/row, 16B each
    int nB = tid >> 2, sgB = tid & 3;      // B: 4 threads/row, 16 elems each

    for (int kk = 0; kk < H_; kk += 64) {
        #pragma unroll
        for (int rr = 0; rr < 64; rr += 32) {
            int r = rA + rr;
            int tk = ls_tk[r];
            uint4 v = make_uint4(0u, 0u, 0u, 0u);
            if (tk >= 0)
                v = *(const uint4*)(normed_bf + (size_t)(tk >> 1) * H_ + kk + sgA * 8);
            *(uint4*)(&lA[r * LDST + sgA * 8]) = v;
        }
        if (PRE) {
            const unsigned short* srcg = w1b + w1base + (size_t)(it0 + nB) * H_ + kk + sgB * 16;
            const unsigned short* srcl = srcg + (size_t)I_ * H_;
            *(uint4*)(&lBg[nB * LDST + sgB * 16])     = ((const uint4*)srcg)[0];
            *(uint4*)(&lBg[nB * LDST + sgB * 16 + 8]) = ((const uint4*)srcg)[1];
            *(uint4*)(&lBl[nB * LDST + sgB * 16])     = ((const uint4*)srcl)[0];
            *(uint4*)(&lBl[nB * LDST + sgB * 16 + 8]) = ((const uint4*)srcl)[1];
        } else {
            const float* srcg = w1f + w1base + (size_t)(it0 + nB) * H_ + kk + sgB * 16;
            const float* srcl = srcg + (size_t)I_ * H_;
            unsigned short tg[16], tl[16];
            #pragma unroll
            for (int q = 0; q < 4; q++) {
                float4 fg = ((const float4*)srcg)[q];
                float4 fl = ((const float4*)srcl)[q];
                tg[q*4+0] = f2bf(fg.x); tg[q*4+1] = f2bf(fg.y);
                tg[q*4+2] = f2bf(fg.z); tg[q*4+3] = f2bf(fg.w);
                tl[q*4+0] = f2bf(fl.x); tl[q*4+1] = f2bf(fl.y);
                tl[q*4+2] = f2bf(fl.z); tl[q*4+3] = f2bf(fl.w);
            }
            *(uint4*)(&lBg[nB * LDST + sgB * 16])     = *(uint4*)(&tg[0]);
            *(uint4*)(&lBg[nB * LDST + sgB * 16 + 8]) = *(uint4*)(&tg[8]);
            *(uint4*)(&lBl[nB * LDST + sgB * 16])     = *(uint4*)(&tl[0]);
            *(uint4*)(&lBl[nB * LDST + sgB * 16 + 8]) = *(uint4*)(&tl[8]);
        }
        __syncthreads();
        #pragma unroll
        for (int ks = 0; ks < 64; ks += 32) {
            bf16x8 af = *(const bf16x8*)(&lA[(wave * 16 + m16) * LDST + ks + quad * 8]);
            #pragma unroll
            for (int ns = 0; ns < 4; ns++) {
                bf16x8 bg = *(const bf16x8*)(&lBg[(ns * 16 + m16) * LDST + ks + quad * 8]);
                accg[ns] = __builtin_amdgcn_mfma_f32_16x16x32_bf16(af, bg, accg[ns], 0, 0, 0);
                bf16x8 bl = *(const bf16x8*)(&lBl[(ns * 16 + m16) * LDST + ks + quad * 8]);
                accl[ns] = __builtin_amdgcn_mfma_f32_16x16x32_bf16(af, bl, accl[ns], 0, 0, 0);
            }
        }
        __syncthreads();
    }

    #pragma unroll
    for (int reg = 0; reg < 4; reg++) {
        int row = wave * 16 + quad * 4 + reg;
        int tk = ls_tk[row];
        if (tk < 0) continue;
        #pragma unroll
        for (int ns = 0; ns < 4; ns++) {
            int i = it0 + ns * 16 + m16;
            float g = accg[ns][reg] + b1[(size_t)e * 2 * I_ + i];
            float l = accl[ns][reg] + b1[(size_t)e * 2 * I_ + I_ + i];
            g = fminf(g, 7.f);
            l = fminf(fmaxf(l, -7.f), 7.f);
            float sw = g / (1.f + expf(-1.702f * g));
            float a = sw * (l + 1.f);
            act[(size_t)tk * I_ + i] = f2bf(a);
        }
    }
}

// ---------------- Kernel 4: GEMM2 (act x W2^T), weighted scatter-add -------
template<bool PRE>
__global__ __launch_bounds__(256) void k_mlp2(
    const float* __restrict__ w2f, const unsigned short* __restrict__ w2b,
    const float* __restrict__ b2,
    const unsigned short* __restrict__ act,
    const int* __restrict__ counts, const int* __restrict__ tok_list,
    const float* __restrict__ w_list,
    float* __restrict__ out)
{
    int e = blockIdx.z;
    int Ne = counts[e];
    int mt0 = blockIdx.y * 64;
    if (mt0 >= Ne) return;
    int ht0 = blockIdx.x * 64;
    int tid = threadIdx.x;
    int lane = tid & 63, wave = tid >> 6;
    int quad = lane >> 4, m16 = lane & 15;

    __shared__ unsigned short lA[64 * LDST];
    __shared__ unsigned short lB[64 * LDST];
    __shared__ int ls_tk[64];
    __shared__ float ls_w[64];

    if (tid < 64) {
        int slot = mt0 + tid;
        ls_tk[tid] = (slot < Ne) ? tok_list[e * T_ + slot] : -1;
        ls_w[tid]  = (slot < Ne) ? w_list[e * T_ + slot] : 0.f;
    }
    __syncthreads();

    f32x4 acc[4];
    #pragma unroll
    for (int ns = 0; ns < 4; ns++) acc[ns] = (f32x4){0.f, 0.f, 0.f, 0.f};

    const size_t w2base = (size_t)e * H_ * I_;
    int rA = tid >> 3, sgA = tid & 7;
    int nB = tid >> 2, sgB = tid & 3;

    for (int kk = 0; kk < I_; kk += 64) {
        #pragma unroll
        for (int rr = 0; rr < 64; rr += 32) {
            int r = rA + rr;
            int tk = ls_tk[r];
            uint4 v = make_uint4(0u, 0u, 0u, 0u);
            if (tk >= 0)
                v = *(const uint4*)(act + (size_t)tk * I_ + kk + sgA * 8);
            *(uint4*)(&lA[r * LDST + sgA * 8]) = v;
        }
        if (PRE) {
            const unsigned short* src = w2b + w2base + (size_t)(ht0 + nB) * I_ + kk + sgB * 16;
            *(uint4*)(&lB[nB * LDST + sgB * 16])     = ((const uint4*)src)[0];
            *(uint4*)(&lB[nB * LDST + sgB * 16 + 8]) = ((const uint4*)src)[1];
        } else {
            const float* src = w2f + w2base + (size_t)(ht0 + nB) * I_ + kk + sgB * 16;
            unsigned short tb[16];
            #pragma unroll
            for (int q = 0; q < 4; q++) {
                float4 f4 = ((const float4*)src)[q];
                tb[q*4+0] = f2bf(f4.x); tb[q*4+1] = f2bf(f4.y);
                tb[q*4+2] = f2bf(f4.z); tb[q*4+3] = f2bf(f4.w);
            }
            *(uint4*)(&lB[nB * LDST + sgB * 16])     = *(uint4*)(&tb[0]);
            *(uint4*)(&lB[nB * LDST + sgB * 16 + 8]) = *(uint4*)(&tb[8]);
        }
        __syncthreads();
        #pragma unroll
        for (int ks = 0; ks < 64; ks += 32) {
            bf16x8 af = *(const bf16x8*)(&lA[(wave * 16 + m16) * LDST + ks + quad * 8]);
            #pragma unroll
            for (int ns = 0; ns < 4; ns++) {
                bf16x8 bf = *(const bf16x8*)(&lB[(ns * 16 + m16) * LDST + ks + quad * 8]);
                acc[ns] = __builtin_amdgcn_mfma_f32_16x16x32_bf16(af, bf, acc[ns], 0, 0, 0);
            }
        }
        __syncthreads();
    }

    #pragma unroll
    for (int reg = 0; reg < 4; reg++) {
        int row = wave * 16 + quad * 4 + reg;
        int tk = ls_tk[row];
        if (tk < 0) continue;
        int t = tk >> 1;
        float wgt = ls_w[row];
        #pragma unroll
        for (int ns = 0; ns < 4; ns++) {
            int h = ht0 + ns * 16 + m16;
            float v = acc[ns][reg] + b2[(size_t)e * H_ + h];
            atomicAdd(&out[(size_t)t * H_ + h], wgt * v);
        }
    }
}

// ---------------- launcher -------------------------------------------------
extern "C" void kernel_launch(void* const* d_in, const int* in_sizes, int n_in,
                              void* d_out, int out_size, void* d_ws, size_t ws_size,
                              hipStream_t stream) {
    const float* x     = (const float*)d_in[0];
    const float* scale = (const float*)d_in[1];
    const float* gk    = (const float*)d_in[2];
    const float* gb    = (const float*)d_in[3];
    const float* w1    = (const float*)d_in[4];
    const float* b1    = (const float*)d_in[5];
    const float* w2    = (const float*)d_in[6];
    const float* b2    = (const float*)d_in[7];
    float* out = (float*)d_out;

    char* ws = (char*)d_ws;
    const size_t MB = 1024 * 1024;
    bool pre = ws_size >= (size_t)138 * MB;

    unsigned short* normed_bf = (unsigned short*)ws;                    // 8 MB
    unsigned short* act       = (unsigned short*)(ws + 8 * MB);         // 32 MB
    unsigned short* w1b = nullptr;
    unsigned short* w2b = nullptr;
    char* ctl;
    if (pre) {
        w1b = (unsigned short*)(ws + 40 * MB);    // 64 MB
        w2b = (unsigned short*)(ws + 104 * MB);   // 32 MB
        ctl = ws + 136 * MB;
    } else {
        ctl = ws + 40 * MB;
    }
    int*   counts   = (int*)ctl;
    int*   tok_list = (int*)(ctl + 256);
    float* w_list   = (float*)(ctl + 256 + (size_t)E_ * T_ * 4);

    hipMemsetAsync(counts, 0, E_ * sizeof(int), stream);

    k_norm_gate<<<dim3(T_), dim3(256), 0, stream>>>(x, scale, gk, gb,
                                                    normed_bf, counts, tok_list, w_list);
    if (pre) {
        k_convert<<<dim3((E_ * 2 * I_ * H_) / (256 * 8)), dim3(256), 0, stream>>>(w1, w1b);
        k_convert<<<dim3((E_ * H_ * I_) / (256 * 8)), dim3(256), 0, stream>>>(w2, w2b);
    }
    k_init_out<<<dim3(T_ * H_ / (256 * 4)), dim3(256), 0, stream>>>(x, out);

    if (pre) {
        k_mlp1<true><<<dim3(I_ / 64, T_ / 64, E_), dim3(256), 0, stream>>>(
            nullptr, w1b, b1, normed_bf, counts, tok_list, act);
        k_mlp2<true><<<dim3(H_ / 64, T_ / 64, E_), dim3(256), 0, stream>>>(
            nullptr, w2b, b2, act, counts, tok_list, w_list, out);
    } else {
        k_mlp1<false><<<dim3(I_ / 64, T_ / 64, E_), dim3(256), 0, stream>>>(
            w1, nullptr, b1, normed_bf, counts, tok_list, act);
        k_mlp2<false><<<dim3(H_ / 64, T_ / 64, E_), dim3(256), 0, stream>>>(
            w2, nullptr, b2, act, counts, tok_list, w_list, out);
    }
}